// Round 14
// baseline (200.868 us; speedup 1.0000x reference)
//
#include <hip/hip_runtime.h>

// STKBranch double-softmax attention, R14: R13 (32x32x16 MFMA, key-interleaved P,
// global_load_lds staging) with 8-wave blocks + Qs/Ps LDS union:
//   ROWS=256, 512 thr, grid 256 (1 block/CU) -> 16 waves/CU (R13 had 8).
//   Qs (dead after A-frag load) shares LDS with Ps (live only in pass 2).
// Math: L = scale*q@k^T ; w = softmax(2L) ; attn = softmax(L*w) ; out = attn@v
// |L| <= ~7 -> no max-subtraction. B=4 H=8 N=2048 D=64 fp32 io.

typedef _Float16 f16;
typedef f16 f16x8 __attribute__((ext_vector_type(8)));
typedef float f32x16 __attribute__((ext_vector_type(16)));

#define MFMA32(a, b, c) __builtin_amdgcn_mfma_f32_32x32x16_f16((a), (b), (c), 0, 0, 0)
#define EXP2(x) __builtin_amdgcn_exp2f(x)   // v_exp_f32: D = 2^S0

#define N_CTX 2048
#define DH 64
#define KT 64
#define NKT (N_CTX / KT)
#define ROWS 256          // 8 waves x 32 q-rows
#define QS 72             // Qs/Ps row stride (f16)
#define HEAD_ELEMS (N_CTX * DH)
#define C2 2.885390081777927f     // 2*log2(e), folded into staged Q

__device__ inline unsigned pk(float a, float b) {
    typedef __fp16 fp16x2_t __attribute__((ext_vector_type(2)));
    union { fp16x2_t v; unsigned u; } x;
    x.v = __builtin_amdgcn_cvt_pkrtz(a, b);
    return x.u;
}

__device__ inline void load16_lds(const f16* g, f16* l) {
    __builtin_amdgcn_global_load_lds(
        (const __attribute__((address_space(1))) void*)g,
        (__attribute__((address_space(3))) void*)l, 16, 0, 0);
}

// ---- pass0: K f32->f16 same layout; V f32 -> f16 [h][d][ik] interleaved ----
__global__ __launch_bounds__(256)
void cvt_kv(const float* __restrict__ k, const float* __restrict__ v,
            f16* __restrict__ ko, f16* __restrict__ vto) {
    __shared__ float Vs[64][65];
    const int bh = blockIdx.x & 31;
    const int kt = blockIdx.x >> 5;
    const int t  = threadIdx.x;
    const float* kb = k + (size_t)bh * HEAD_ELEMS + (size_t)kt * KT * DH;
    f16* kob = ko + (size_t)bh * HEAD_ELEMS + (size_t)kt * KT * DH;
    #pragma unroll
    for (int it = 0; it < 2; ++it) {
        int i = (it * 256 + t) * 8;
        float4 a = *(const float4*)&kb[i];
        float4 b = *(const float4*)&kb[i + 4];
        *(uint4*)&kob[i] = make_uint4(pk(a.x, a.y), pk(a.z, a.w), pk(b.x, b.y), pk(b.z, b.w));
    }
    const float* vb = v + (size_t)bh * HEAD_ELEMS + (size_t)kt * KT * DH;
    #pragma unroll
    for (int it = 0; it < 4; ++it) {
        int idx = it * 256 + t;
        int row = idx >> 4, c4 = idx & 15;
        *(float4*)&Vs[row][c4 * 4] = *(const float4*)&vb[row * DH + c4 * 4];
    }
    __syncthreads();
    // thread t: d = t>>2, writes ik = sub*16 .. +15  (ik=2c -> key c, ik=2c+1 -> key c+32)
    int d = t >> 2, sub = t & 3;
    unsigned w[8];
    #pragma unroll
    for (int j = 0; j < 8; ++j) {
        int c = sub * 8 + j;
        w[j] = pk(Vs[c][d], Vs[c + 32][d]);
    }
    f16* ob = vto + (size_t)bh * HEAD_ELEMS + (size_t)d * N_CTX + kt * KT + sub * 16;
    *(uint4*)(ob)     = make_uint4(w[0], w[1], w[2], w[3]);
    *(uint4*)(ob + 8) = make_uint4(w[4], w[5], w[6], w[7]);
}

// ---- main ----
__global__ __launch_bounds__(512, 4)
void stk_attn_mfma(const float* __restrict__ qg, const f16* __restrict__ kh,
                   const f16* __restrict__ vth, const float* __restrict__ sg,
                   float* __restrict__ og) {
    __shared__ f16 QsPs[ROWS * QS];     // 36864 B: Qs (prologue) then Ps (pass 2)
    __shared__ f16 Ks[2][KT * DH];      // 16384 B chunk-swizzled: p = key*8 + (dc^(key&7))
    __shared__ f16 Vt[2][DH * KT];      // 16384 B chunk-swizzled: p = d*8 + (ikc^(d&7))
                                        // total 69632 B; grid 256 -> 1 block/CU, 16 waves

    const int tid  = threadIdx.x;
    const int wv   = tid >> 6;        // 0..7
    const int lane = tid & 63;
    const int l31  = lane & 31;
    const int lh   = lane >> 5;       // 0/1
    const int bh   = blockIdx.x & 31; // XCD swizzle
    const int q0   = (blockIdx.x >> 5) * ROWS;
    const float scale2 = sg[0] * C2;  // acc = 2L*log2e

    const float* qb = qg + (size_t)bh * HEAD_ELEMS;
    const f16*   kb = kh + (size_t)bh * HEAD_ELEMS;
    const f16*   vtb = vth + (size_t)bh * HEAD_ELEMS;
    float*       ob = og + (size_t)bh * HEAD_ELEMS;

    // ---- stage Q (scale2 folded) into QsPs ----
    #pragma unroll
    for (int it = 0; it < 8; ++it) {
        int idx = it * 512 + tid;
        int row = idx >> 4, c4 = idx & 15;
        float4 v = *(const float4*)&qb[((size_t)(q0 + row)) * DH + c4 * 4];
        *(uint2*)&QsPs[row * QS + c4 * 4] =
            make_uint2(pk(v.x * scale2, v.y * scale2), pk(v.z * scale2, v.w * scale2));
    }
    __syncthreads();

    // ---- Q A-frags: A[m=l31][k = km*16 + lh*8 + j]; Qs dead afterwards ----
    f16x8 aq[4];
    #pragma unroll
    for (int km = 0; km < 4; ++km)
        aq[km] = *(const f16x8*)&QsPs[(wv * 32 + l31) * QS + km * 16 + lh * 8];

    // ---- staging src offsets (XOR chunk swizzle) & LDS read offsets ----
    const int c0   = wv * 64 + lane;            // 512 chunks = one 8 KB tile
    const int key0 = c0 >> 3;
    const int swz  = ((c0 & 7) ^ (key0 & 7)) * 8;
    const int ks_src0 = key0 * DH + swz;
    const long vt_src0 = (long)key0 * N_CTX + swz;
    const int dst0 = wv * 512;                  // wave-uniform LDS base (f16)
    const int x8 = l31 & 7;
    int xo[4];
    #pragma unroll
    for (int km = 0; km < 4; ++km) xo[km] = ((2 * km + lh) ^ x8) * 8;
    const int gb0 = l31 * 64, gb1 = (32 + l31) * 64;   // key/d group bases
    f16* const ps_wv = &QsPs[wv * 32 * QS];            // Ps alias (pass 2 only)

    // =============== PASS 1: s1 = sum exp(2L) ===============
    float s1[16] = {0};
    load16_lds(kb + ks_src0, &Ks[0][dst0]);
    __syncthreads();
    for (int kt = 0; kt < NKT; ++kt) {
        const int cur = kt & 1;
        if (kt + 1 < NKT)
            load16_lds(kb + (kt + 1) * (KT * DH) + ks_src0, &Ks[cur ^ 1][dst0]);
        #pragma unroll
        for (int kg = 0; kg < 2; ++kg) {
            const int gb = kg ? gb1 : gb0;
            f32x16 acc;
            #pragma unroll
            for (int i = 0; i < 16; ++i) acc[i] = 0.f;
            #pragma unroll
            for (int km = 0; km < 4; ++km) {
                f16x8 b = *(const f16x8*)&Ks[cur][gb + xo[km]];
                acc = MFMA32(aq[km], b, acc);
            }
            #pragma unroll
            for (int r = 0; r < 16; ++r)
                s1[r] += EXP2(acc[r]);
        }
        __syncthreads();   // drains global_load_lds for Ks[nxt] + protects swap
    }
    float inv1[16];
    #pragma unroll
    for (int r = 0; r < 16; ++r) {
        float v = s1[r];
        v += __shfl_xor(v, 1, 64);
        v += __shfl_xor(v, 2, 64);
        v += __shfl_xor(v, 4, 64);
        v += __shfl_xor(v, 8, 64);
        v += __shfl_xor(v, 16, 64);   // 32 cols of a row live in one 32-lane half
        inv1[r] = 0.5f / v;           // e2 = exp2((acc*e1) * 0.5/s1)
    }

    // =============== PASS 2: e2, O += e2*V ===============
    float l2[16] = {0};
    f32x16 O0, O1;
    #pragma unroll
    for (int i = 0; i < 16; ++i) { O0[i] = 0.f; O1[i] = 0.f; }

    load16_lds(kb + ks_src0, &Ks[0][dst0]);
    load16_lds(vtb + vt_src0, &Vt[0][dst0]);
    __syncthreads();
    for (int kt = 0; kt < NKT; ++kt) {
        const int cur = kt & 1;
        if (kt + 1 < NKT) {
            load16_lds(kb + (kt + 1) * (KT * DH) + ks_src0, &Ks[cur ^ 1][dst0]);
            load16_lds(vtb + vt_src0 + (kt + 1) * KT, &Vt[cur ^ 1][dst0]);
        }
        // QK^T: two 32-key groups
        f32x16 a0, a1;
        #pragma unroll
        for (int i = 0; i < 16; ++i) { a0[i] = 0.f; a1[i] = 0.f; }
        #pragma unroll
        for (int km = 0; km < 4; ++km) {
            f16x8 b0 = *(const f16x8*)&Ks[cur][gb0 + xo[km]];
            f16x8 b1 = *(const f16x8*)&Ks[cur][gb1 + xo[km]];
            a0 = MFMA32(aq[km], b0, a0);
            a1 = MFMA32(aq[km], b1, a1);
        }
        // softmax chain + packed b32 Ps write (ik = 2*col + kg)
        #pragma unroll
        for (int r = 0; r < 16; ++r) {
            int row_r = (r & 3) + 8 * (r >> 2) + 4 * lh;
            float e10 = EXP2(a0[r]);
            float e20 = EXP2((a0[r] * e10) * inv1[r]);
            float e11 = EXP2(a1[r]);
            float e21 = EXP2((a1[r] * e11) * inv1[r]);
            l2[r] += e20 + e21;
            *(unsigned*)&ps_wv[row_r * QS + 2 * l31] = pk(e20, e21);
        }
        // PV: A = P[m=l31][ik], B = Vt[ik][d]
        #pragma unroll
        for (int km = 0; km < 4; ++km) {
            f16x8 ap = *(const f16x8*)&ps_wv[l31 * QS + km * 16 + lh * 8];
            f16x8 bv0 = *(const f16x8*)&Vt[cur][gb0 + xo[km]];
            f16x8 bv1 = *(const f16x8*)&Vt[cur][gb1 + xo[km]];
            O0 = MFMA32(ap, bv0, O0);
            O1 = MFMA32(ap, bv1, O1);
        }
        __syncthreads();   // protects Ks/Vt swap; drains global_load_lds
    }

    // ---- finalize ----
    float invl2[16];
    #pragma unroll
    for (int r = 0; r < 16; ++r) {
        float v = l2[r];
        v += __shfl_xor(v, 1, 64);
        v += __shfl_xor(v, 2, 64);
        v += __shfl_xor(v, 4, 64);
        v += __shfl_xor(v, 8, 64);
        v += __shfl_xor(v, 16, 64);
        invl2[r] = 1.0f / v;
    }
    #pragma unroll
    for (int r = 0; r < 16; ++r) {
        int row = q0 + wv * 32 + (r & 3) + 8 * (r >> 2) + 4 * lh;
        ob[(size_t)row * DH + l31]      = O0[r] * invl2[r];
        ob[(size_t)row * DH + 32 + l31] = O1[r] * invl2[r];
    }
}

extern "C" void kernel_launch(void* const* d_in, const int* in_sizes, int n_in,
                              void* d_out, int out_size, void* d_ws, size_t ws_size,
                              hipStream_t stream) {
    const float* q = (const float*)d_in[0];
    const float* k = (const float*)d_in[1];
    const float* v = (const float*)d_in[2];
    const float* s = (const float*)d_in[3];
    float* out = (float*)d_out;
    f16* kf  = (f16*)d_ws;                             // 8,388,608 B
    f16* vtf = (f16*)((char*)d_ws + 8388608);          // 8,388,608 B
    cvt_kv<<<1024, 256, 0, stream>>>(k, v, kf, vtf);
    dim3 grid(32 * 8);    // bh = blockIdx&31 (XCD swizzle), q-tile = blockIdx>>5
    stk_attn_mfma<<<grid, 512, 0, stream>>>(q, kf, vtf, s, out);
}

// Round 15
// 179.312 us; speedup vs baseline: 1.1202x; 1.1202x over previous
//
#include <hip/hip_runtime.h>

// STKBranch double-softmax attention, R15: split-K 32x32 MFMA.
//   8 waves = 4 row-groups x 2 key-halves; wave h does keys h*32..+31 of each tile
//   -> 16 waves/CU (R12 occupancy) with 32x32 MFMA (R13 LDS efficiency).
//   s1/l2/O combined across wave pairs via LDS (once per pass).
//   K/V staged via global_load_lds, source-XOR chunk swizzle; 1 barrier/tile.
// Math: L = scale*q@k^T ; w = softmax(2L) ; attn = softmax(L*w) ; out = attn@v
// |L| <= ~7 -> no max-subtraction. B=4 H=8 N=2048 D=64 fp32 io.

typedef _Float16 f16;
typedef f16 f16x8 __attribute__((ext_vector_type(8)));
typedef float f32x16 __attribute__((ext_vector_type(16)));

#define MFMA32(a, b, c) __builtin_amdgcn_mfma_f32_32x32x16_f16((a), (b), (c), 0, 0, 0)
#define EXP2(x) __builtin_amdgcn_exp2f(x)   // v_exp_f32: D = 2^S0

#define N_CTX 2048
#define DH 64
#define KT 64
#define NKT (N_CTX / KT)
#define ROWS 128          // 4 row-groups x 32 rows
#define QS 72             // Qs row stride (f16)
#define PSS 40            // Ps row stride (f16): 80 B, multiple of 16 B
#define HEAD_ELEMS (N_CTX * DH)
#define C2 2.885390081777927f     // 2*log2(e), folded into staged Q

__device__ inline unsigned pk(float a, float b) {
    typedef __fp16 fp16x2_t __attribute__((ext_vector_type(2)));
    union { fp16x2_t v; unsigned u; } x;
    x.v = __builtin_amdgcn_cvt_pkrtz(a, b);
    return x.u;
}

__device__ inline void load16_lds(const f16* g, f16* l) {
    __builtin_amdgcn_global_load_lds(
        (const __attribute__((address_space(1))) void*)g,
        (__attribute__((address_space(3))) void*)l, 16, 0, 0);
}

// ---- pass0: K f32->f16 same layout; V f32 -> f16 transposed [h][d][key] ----
__global__ __launch_bounds__(256)
void cvt_kv(const float* __restrict__ k, const float* __restrict__ v,
            f16* __restrict__ ko, f16* __restrict__ vto) {
    __shared__ float Vs[64][65];
    const int bh = blockIdx.x & 31;
    const int kt = blockIdx.x >> 5;
    const int t  = threadIdx.x;
    const float* kb = k + (size_t)bh * HEAD_ELEMS + (size_t)kt * KT * DH;
    f16* kob = ko + (size_t)bh * HEAD_ELEMS + (size_t)kt * KT * DH;
    #pragma unroll
    for (int it = 0; it < 2; ++it) {
        int i = (it * 256 + t) * 8;
        float4 a = *(const float4*)&kb[i];
        float4 b = *(const float4*)&kb[i + 4];
        *(uint4*)&kob[i] = make_uint4(pk(a.x, a.y), pk(a.z, a.w), pk(b.x, b.y), pk(b.z, b.w));
    }
    const float* vb = v + (size_t)bh * HEAD_ELEMS + (size_t)kt * KT * DH;
    #pragma unroll
    for (int it = 0; it < 4; ++it) {
        int idx = it * 256 + t;
        int row = idx >> 4, c4 = idx & 15;
        *(float4*)&Vs[row][c4 * 4] = *(const float4*)&vb[row * DH + c4 * 4];
    }
    __syncthreads();
    int d = t >> 2, sub = t & 3;
    unsigned w[8];
    #pragma unroll
    for (int j = 0; j < 8; ++j)
        w[j] = pk(Vs[sub * 16 + 2 * j][d], Vs[sub * 16 + 2 * j + 1][d]);
    f16* ob = vto + (size_t)bh * HEAD_ELEMS + (size_t)d * N_CTX + kt * KT + sub * 16;
    *(uint4*)(ob)     = make_uint4(w[0], w[1], w[2], w[3]);
    *(uint4*)(ob + 8) = make_uint4(w[4], w[5], w[6], w[7]);
}

// ---- main ----
__global__ __launch_bounds__(512, 4)
void stk_attn_mfma(const float* __restrict__ qg, const f16* __restrict__ kh,
                   const f16* __restrict__ vth, const float* __restrict__ sg,
                   float* __restrict__ og) {
    // manual carve for precise layout + Ored overlay of dead Ks/Vt
    __shared__ __align__(16) unsigned char smem[72704];
    f16* const Qs   = (f16*)(smem);                 // 18432 B
    f16* const KsB  = (f16*)(smem + 18432);         // 16384 B: Ks[2][64*64]
    f16* const VtB  = (f16*)(smem + 34816);         // 16384 B: Vt[2][64*64]
    f16* const PsB  = (f16*)(smem + 51200);         // 20480 B: Ps[8][32*PSS]
    float* const sred = (float*)(smem + 71680);     //  1024 B: sred[4][2][32]
    float* const Ored = (float*)(smem + 18432);     // 32768 B overlay (after loops)

    const int tid  = threadIdx.x;
    const int wv   = tid >> 6;        // 0..7
    const int lane = tid & 63;
    const int l31  = lane & 31;
    const int lh   = lane >> 5;       // 0/1
    const int rg   = wv >> 1;         // row group 0..3
    const int h    = wv & 1;          // key half 0/1
    const int bh   = blockIdx.x & 31; // XCD swizzle
    const int q0   = (blockIdx.x >> 5) * ROWS;
    const float scale2 = sg[0] * C2;  // acc = 2L*log2e

    const float* qb  = qg + (size_t)bh * HEAD_ELEMS;
    const f16*   kb  = kh + (size_t)bh * HEAD_ELEMS;
    const f16*   vtb = vth + (size_t)bh * HEAD_ELEMS;
    float*       ob  = og + (size_t)bh * HEAD_ELEMS;

    // ---- stage Q (scale2 folded) ----
    #pragma unroll
    for (int it = 0; it < 4; ++it) {
        int idx = it * 512 + tid;
        int row = idx >> 4, c4 = idx & 15;
        float4 v = *(const float4*)&qb[((size_t)(q0 + row)) * DH + c4 * 4];
        *(uint2*)&Qs[row * QS + c4 * 4] =
            make_uint2(pk(v.x * scale2, v.y * scale2), pk(v.z * scale2, v.w * scale2));
    }
    __syncthreads();

    // ---- Q A-frags: A[m=l31][k = km*16 + lh*8 + j] (rows rg*32+l31) ----
    f16x8 aq[4];
    #pragma unroll
    for (int km = 0; km < 4; ++km)
        aq[km] = *(const f16x8*)&Qs[(rg * 32 + l31) * QS + km * 16 + lh * 8];

    // ---- staging offsets (XOR chunk swizzle) & read offsets ----
    const int c0   = wv * 64 + lane;            // 512 chunks = one 8 KB tile
    const int key0 = c0 >> 3;
    const int swz  = ((c0 & 7) ^ (key0 & 7)) * 8;
    const int ks_src0 = key0 * DH + swz;
    const long vt_src0 = (long)key0 * N_CTX + swz;
    const int dst0 = wv * 512;                  // wave-uniform LDS chunk base (f16)
    // K B-frags (QK^T): key = h*32+l31, d-chunk 2km+lh
    const int kbase = (h * 32 + l31) * 64;
    const int x8 = l31 & 7;
    int xo[4];
    #pragma unroll
    for (int km = 0; km < 4; ++km) xo[km] = ((2 * km + lh) ^ x8) * 8;
    // V B-frags (PV): d = g*32+l31, key chunk kc = h*4 + km*2 + lh
    int vxo[2][2];
    #pragma unroll
    for (int g = 0; g < 2; ++g)
        #pragma unroll
        for (int km = 0; km < 2; ++km)
            vxo[g][km] = (g * 32 + l31) * 64 + (((h * 4 + km * 2 + lh) ^ x8) * 8);
    f16* const ps_wv = PsB + wv * (32 * PSS);

    // =============== PASS 1: s1 = sum exp(2L) ===============
    float s1[16] = {0};
    load16_lds(kb + ks_src0, KsB + dst0);
    __syncthreads();
    for (int kt = 0; kt < NKT; ++kt) {
        const int cur = (kt & 1) * 4096;
        if (kt + 1 < NKT)
            load16_lds(kb + (kt + 1) * (KT * DH) + ks_src0, KsB + (4096 - cur) + dst0);
        f32x16 acc;
        #pragma unroll
        for (int i = 0; i < 16; ++i) acc[i] = 0.f;
        #pragma unroll
        for (int km = 0; km < 4; ++km) {
            f16x8 b = *(const f16x8*)&KsB[cur + kbase + xo[km]];
            acc = MFMA32(aq[km], b, acc);
        }
        #pragma unroll
        for (int r = 0; r < 16; ++r)
            s1[r] += EXP2(acc[r]);
        __syncthreads();   // drains global_load_lds + protects swap
    }
    // reduce over the wave's 32 key-lanes, then across the h pair via LDS
    #pragma unroll
    for (int r = 0; r < 16; ++r) {
        float v = s1[r];
        v += __shfl_xor(v, 1, 64);
        v += __shfl_xor(v, 2, 64);
        v += __shfl_xor(v, 4, 64);
        v += __shfl_xor(v, 8, 64);
        v += __shfl_xor(v, 16, 64);
        s1[r] = v;
    }
    if (l31 == 0) {
        #pragma unroll
        for (int r = 0; r < 16; ++r)
            sred[(rg * 2 + h) * 32 + (r & 3) + 8 * (r >> 2) + 4 * lh] = s1[r];
    }
    __syncthreads();
    float inv1[16];
    #pragma unroll
    for (int r = 0; r < 16; ++r) {
        int row_r = (r & 3) + 8 * (r >> 2) + 4 * lh;
        float tot = sred[(rg * 2) * 32 + row_r] + sred[(rg * 2 + 1) * 32 + row_r];
        inv1[r] = 0.5f / tot;     // e2 = exp2((acc*e1) * 0.5/s1)  [acc = 2L*log2e]
    }
    __syncthreads();              // sred reads done before l2 reuse

    // =============== PASS 2: e2, O += e2*V ===============
    float l2[16] = {0};
    f32x16 O0, O1;
    #pragma unroll
    for (int i = 0; i < 16; ++i) { O0[i] = 0.f; O1[i] = 0.f; }

    load16_lds(kb + ks_src0, KsB + dst0);
    load16_lds(vtb + vt_src0, VtB + dst0);
    __syncthreads();
    for (int kt = 0; kt < NKT; ++kt) {
        const int cur = (kt & 1) * 4096;
        if (kt + 1 < NKT) {
            load16_lds(kb + (kt + 1) * (KT * DH) + ks_src0, KsB + (4096 - cur) + dst0);
            load16_lds(vtb + vt_src0 + (kt + 1) * KT, VtB + (4096 - cur) + dst0);
        }
        // QK^T on this wave's 32-key half
        f32x16 acc;
        #pragma unroll
        for (int i = 0; i < 16; ++i) acc[i] = 0.f;
        #pragma unroll
        for (int km = 0; km < 4; ++km) {
            f16x8 b = *(const f16x8*)&KsB[cur + kbase + xo[km]];
            acc = MFMA32(aq[km], b, acc);
        }
        // softmax chain + Ps b16 writes (wave-private)
        #pragma unroll
        for (int r = 0; r < 16; ++r) {
            float a  = acc[r];
            float e1 = EXP2(a);
            float e2 = EXP2((a * e1) * inv1[r]);
            l2[r] += e2;
            int row_r = (r & 3) + 8 * (r >> 2) + 4 * lh;
            ps_wv[row_r * PSS + l31] = (f16)e2;
        }
        // PV: A = Ps[m=l31][k=km*16+lh*8+j], B = Vt[k(within half)][d=g*32+l31]
        #pragma unroll
        for (int km = 0; km < 2; ++km) {
            f16x8 ap = *(const f16x8*)&ps_wv[l31 * PSS + km * 16 + lh * 8];
            f16x8 bv0 = *(const f16x8*)&VtB[cur + vxo[0][km]];
            f16x8 bv1 = *(const f16x8*)&VtB[cur + vxo[1][km]];
            O0 = MFMA32(ap, bv0, O0);
            O1 = MFMA32(ap, bv1, O1);
        }
        __syncthreads();   // drains global_load_lds + protects swap
    }

    // ---- combine l2 across h pair ----
    #pragma unroll
    for (int r = 0; r < 16; ++r) {
        float v = l2[r];
        v += __shfl_xor(v, 1, 64);
        v += __shfl_xor(v, 2, 64);
        v += __shfl_xor(v, 4, 64);
        v += __shfl_xor(v, 8, 64);
        v += __shfl_xor(v, 16, 64);
        l2[r] = v;
    }
    if (l31 == 0) {
        #pragma unroll
        for (int r = 0; r < 16; ++r)
            sred[(rg * 2 + h) * 32 + (r & 3) + 8 * (r >> 2) + 4 * lh] = l2[r];
    }
    __syncthreads();
    float invl2[16];
    #pragma unroll
    for (int r = 0; r < 16; ++r) {
        int row_r = (r & 3) + 8 * (r >> 2) + 4 * lh;
        float tot = sred[(rg * 2) * 32 + row_r] + sred[(rg * 2 + 1) * 32 + row_r];
        invl2[r] = 1.0f / tot;
    }

    // ---- combine O across h pair (Ored overlays dead Ks/Vt) ----
    __syncthreads();
    if (h == 1) {
        #pragma unroll
        for (int r = 0; r < 16; ++r) {
            int row_r = (r & 3) + 8 * (r >> 2) + 4 * lh;
            Ored[(rg * 32 + row_r) * 64 + l31]      = O0[r];
            Ored[(rg * 32 + row_r) * 64 + 32 + l31] = O1[r];
        }
    }
    __syncthreads();
    if (h == 0) {
        #pragma unroll
        for (int r = 0; r < 16; ++r) {
            int row_r = (r & 3) + 8 * (r >> 2) + 4 * lh;
            int row = q0 + rg * 32 + row_r;
            float o0 = O0[r] + Ored[(rg * 32 + row_r) * 64 + l31];
            float o1 = O1[r] + Ored[(rg * 32 + row_r) * 64 + 32 + l31];
            ob[(size_t)row * DH + l31]      = o0 * invl2[r];
            ob[(size_t)row * DH + 32 + l31] = o1 * invl2[r];
        }
    }
}

extern "C" void kernel_launch(void* const* d_in, const int* in_sizes, int n_in,
                              void* d_out, int out_size, void* d_ws, size_t ws_size,
                              hipStream_t stream) {
    const float* q = (const float*)d_in[0];
    const float* k = (const float*)d_in[1];
    const float* v = (const float*)d_in[2];
    const float* s = (const float*)d_in[3];
    float* out = (float*)d_out;
    f16* kf  = (f16*)d_ws;                             // 8,388,608 B
    f16* vtf = (f16*)((char*)d_ws + 8388608);          // 8,388,608 B
    cvt_kv<<<1024, 256, 0, stream>>>(k, v, kf, vtf);
    dim3 grid(32 * 16);   // bh = blockIdx&31 (XCD swizzle), q-tile = blockIdx>>5
    stk_attn_mfma<<<grid, 512, 0, stream>>>(q, kf, vtf, s, out);
}